// Round 2
// baseline (204.946 us; speedup 1.0000x reference)
//
#include <hip/hip_runtime.h>
#include <math.h>

#define KNN 16
#define CH 64
#define HID 16
#define NEG_BIG (-3.402823466e+38f)

typedef float        f4v __attribute__((ext_vector_type(4)));
typedef int          i2v __attribute__((ext_vector_type(2)));
typedef int          i4v __attribute__((ext_vector_type(4)));
typedef unsigned int u2v __attribute__((ext_vector_type(2)));

// --- non-temporal (evict-first) helpers: zero-reuse streams must not evict
// --- the gather table from L2. Bit-exact vs normal loads/stores.
__device__ __forceinline__ float4 ntload4(const float4* p) {
    f4v v = __builtin_nontemporal_load((const f4v*)p);
    float4 r; r.x = v.x; r.y = v.y; r.z = v.z; r.w = v.w; return r;
}
__device__ __forceinline__ void ntstore4(float4* p, float4 v) {
    f4v t; t.x = v.x; t.y = v.y; t.z = v.z; t.w = v.w;
    __builtin_nontemporal_store(t, (f4v*)p);
}
__device__ __forceinline__ int2 ntload_i2(const int2* p) {
    i2v v = __builtin_nontemporal_load((const i2v*)p);
    return make_int2(v.x, v.y);
}
__device__ __forceinline__ int4 ntload_i4(const int4* p) {
    i4v v = __builtin_nontemporal_load((const i4v*)p);
    return make_int4(v.x, v.y, v.z, v.w);
}
__device__ __forceinline__ void ntstore_u2(uint2* p, uint2 v) {
    u2v t; t.x = v.x; t.y = v.y;
    __builtin_nontemporal_store(t, (u2v*)p);
}

__device__ __forceinline__ float sigmoidf_(float x) {
    return 1.0f / (1.0f + __expf(-x));
}

// pack two fp32 into bf16x2 (RNE), a in low16, b in high16
__device__ __forceinline__ unsigned int pack_bf2(float a, float b) {
    unsigned int ua = __float_as_uint(a), ub = __float_as_uint(b);
    ua = (ua + 0x7FFFu + ((ua >> 16) & 1u)) >> 16;
    ub = (ub + 0x7FFFu + ((ub >> 16) & 1u)) & 0xFFFF0000u;
    return ua | ub;
}

// unpack 4 packed bf16 -> float4
__device__ __forceinline__ float4 bf4_to_f4(unsigned int lo, unsigned int hi) {
    float4 r;
    r.x = __uint_as_float(lo << 16);
    r.y = __uint_as_float(lo & 0xFFFF0000u);
    r.z = __uint_as_float(hi << 16);
    r.w = __uint_as_float(hi & 0xFFFF0000u);
    return r;
}

// paired fold-reduce across an 8-lane group: A[8],B[8] partials -> lane sub
// ends holding full sums A -> H[sub], B -> H[sub+8].
__device__ __forceinline__ void fold8_2(float A[8], float B[8], int sub) {
    #pragma unroll
    for (int m = 4; m >= 1; m >>= 1) {
        bool hi = (sub & m) != 0;
        #pragma unroll
        for (int i = 0; i < m; ++i) {
            float sA = hi ? A[i] : A[i + m], kA_ = hi ? A[i + m] : A[i];
            A[i] = kA_ + __shfl_xor(sA, m);
            float sB = hi ? B[i] : B[i + m], kB_ = hi ? B[i + m] : B[i];
            B[i] = kB_ + __shfl_xor(sB, m);
        }
    }
}

// Pre-pass: bf16 copy of x_F. nt on both sides: x_F is re-read later (L3 is
// plenty), and dirty xb lines in L2 just become writeback churn inside kA's
// window — push them out promptly; gather read-fills will re-allocate them.
__global__ __launch_bounds__(256) void kX(const float4* __restrict__ xv,
                                          uint2* __restrict__ xb, int n16) {
    int i = blockIdx.x * 256 + threadIdx.x;
    if (i >= n16) return;
    float4 v = ntload4(&xv[i]);
    uint2 r;
    r.x = pack_bf2(v.x, v.y);
    r.y = pack_bf2(v.z, v.w);
    ntstore_u2(&xb[i], r);
}

// Phase A: channel attention. 8 lanes per point (8 points/wave), lane owns 8
// channels (uint4 = 8 bf16, 16B). One bf16 row = 128B = one 8-lane slice ->
// gathers keep the proven dwordx4/1KB-per-inst shape at HALF the bytes.
// R7: kA is fetch-bound; fetch = gather misses (~94 MB) + own-row fp32
// (25.6 MB). R6 proved the gather hit rate is set by L2 residency competition
// (removing the fp32 stream just grew the miss term). So: keep the R0
// structure bit-exact, but mark every zero-reuse stream nt (own rows, idx,
// outse stores) so the bf16 table keeps L2 residency. Gathers stay cacheable.
__global__ __launch_bounds__(256, 3) void kA(const float4* __restrict__ xv,
        const uint4* __restrict__ xb4,
        const float* __restrict__ W1, const float* __restrict__ b1,
        const float* __restrict__ W2, const float* __restrict__ b2,
        const int2* __restrict__ idx2,
        float4* __restrict__ outse, float2* __restrict__ rowstat, int n) {
    __shared__ float4 w1a[128];   // w1a[h*8+s] = W1[(8s+0..3)][h]
    __shared__ float4 w1b[128];   // w1b[h*8+s] = W1[(8s+4..7)][h]
    __shared__ float4 w2q[256];   // float4 copy of W2 (16x64 row-major)
    int t = threadIdx.x;
    if (t < 128) {
        int h = t >> 3, s = t & 7;
        float4 a, b;
        a.x = W1[(8 * s + 0) * HID + h];
        a.y = W1[(8 * s + 1) * HID + h];
        a.z = W1[(8 * s + 2) * HID + h];
        a.w = W1[(8 * s + 3) * HID + h];
        b.x = W1[(8 * s + 4) * HID + h];
        b.y = W1[(8 * s + 5) * HID + h];
        b.z = W1[(8 * s + 6) * HID + h];
        b.w = W1[(8 * s + 7) * HID + h];
        w1a[t] = a;
        w1b[t] = b;
    }
    w2q[t] = ((const float4*)W2)[t];
    __syncthreads();

    int p = blockIdx.x * 32 + (t >> 3);
    int sub = t & 7;
    if (p >= n) return;

    // 16 neighbor indices live as int2 per lane; broadcast via width-8 shfl
    int2 jp = ntload_i2(&idx2[(size_t)p * 8 + sub]);
    int jA[8], jB[8];
    #pragma unroll
    for (int s = 0; s < 8; ++s) {
        jA[s] = __shfl(jp.x, s, 8);
        jB[s] = __shfl(jp.y, s, 8);
    }

    // issue all 16 gathers + own-row/bias loads, then pin with sched_barrier
    // (serialized issue measured 0.7 TB/s vs ~2.0 TB/s batched)
    uint4 va[8], vb[8];
    #pragma unroll
    for (int s = 0; s < 8; ++s) va[s] = xb4[(size_t)jA[s] * 8 + sub];
    #pragma unroll
    for (int s = 0; s < 8; ++s) vb[s] = xb4[(size_t)jB[s] * 8 + sub];
    float4 own0 = ntload4(&xv[(size_t)p * 16 + 2 * sub]);
    float4 own1 = ntload4(&xv[(size_t)p * 16 + 2 * sub + 1]);
    float b1a = b1[sub], b1b = b1[sub + 8];
    float4 bq0 = ((const float4*)b2)[2 * sub];
    float4 bq1 = ((const float4*)b2)[2 * sub + 1];
    __builtin_amdgcn_sched_barrier(0);

    float4 sumLo, sumHi, mxLo, mxHi;
    {
        float4 lo = bf4_to_f4(va[0].x, va[0].y);
        float4 hi = bf4_to_f4(va[0].z, va[0].w);
        sumLo = lo; mxLo = lo; sumHi = hi; mxHi = hi;
    }
    #pragma unroll
    for (int s = 1; s < 8; ++s) {
        float4 lo = bf4_to_f4(va[s].x, va[s].y);
        float4 hi = bf4_to_f4(va[s].z, va[s].w);
        sumLo.x += lo.x; sumLo.y += lo.y; sumLo.z += lo.z; sumLo.w += lo.w;
        sumHi.x += hi.x; sumHi.y += hi.y; sumHi.z += hi.z; sumHi.w += hi.w;
        mxLo.x = fmaxf(mxLo.x, lo.x); mxLo.y = fmaxf(mxLo.y, lo.y);
        mxLo.z = fmaxf(mxLo.z, lo.z); mxLo.w = fmaxf(mxLo.w, lo.w);
        mxHi.x = fmaxf(mxHi.x, hi.x); mxHi.y = fmaxf(mxHi.y, hi.y);
        mxHi.z = fmaxf(mxHi.z, hi.z); mxHi.w = fmaxf(mxHi.w, hi.w);
    }
    #pragma unroll
    for (int s = 0; s < 8; ++s) {
        float4 lo = bf4_to_f4(vb[s].x, vb[s].y);
        float4 hi = bf4_to_f4(vb[s].z, vb[s].w);
        sumLo.x += lo.x; sumLo.y += lo.y; sumLo.z += lo.z; sumLo.w += lo.w;
        sumHi.x += hi.x; sumHi.y += hi.y; sumHi.z += hi.z; sumHi.w += hi.w;
        mxLo.x = fmaxf(mxLo.x, lo.x); mxLo.y = fmaxf(mxLo.y, lo.y);
        mxLo.z = fmaxf(mxLo.z, lo.z); mxLo.w = fmaxf(mxLo.w, lo.w);
        mxHi.x = fmaxf(mxHi.x, hi.x); mxHi.y = fmaxf(mxHi.y, hi.y);
        mxHi.z = fmaxf(mxHi.z, hi.z); mxHi.w = fmaxf(mxHi.w, hi.w);
    }
    const float inv_k = 1.0f / KNN;
    float4 meLo = {sumLo.x * inv_k, sumLo.y * inv_k, sumLo.z * inv_k, sumLo.w * inv_k};
    float4 meHi = {sumHi.x * inv_k, sumHi.y * inv_k, sumHi.z * inv_k, sumHi.w * inv_k};

    // layer 1: mean path then max path; fold over the 8-lane group
    float Hm_a, Hm_b, Hx_a, Hx_b;
    {
        float A[8], B[8];
        #pragma unroll
        for (int h = 0; h < 8; ++h) {
            float4 wa = w1a[h * 8 + sub], wb = w1b[h * 8 + sub];
            A[h] = meLo.x * wa.x + meLo.y * wa.y + meLo.z * wa.z + meLo.w * wa.w
                 + meHi.x * wb.x + meHi.y * wb.y + meHi.z * wb.z + meHi.w * wb.w;
            float4 wa2 = w1a[(h + 8) * 8 + sub], wb2 = w1b[(h + 8) * 8 + sub];
            B[h] = meLo.x * wa2.x + meLo.y * wa2.y + meLo.z * wa2.z + meLo.w * wa2.w
                 + meHi.x * wb2.x + meHi.y * wb2.y + meHi.z * wb2.z + meHi.w * wb2.w;
        }
        fold8_2(A, B, sub);
        Hm_a = A[0]; Hm_b = B[0];
    }
    {
        float A[8], B[8];
        #pragma unroll
        for (int h = 0; h < 8; ++h) {
            float4 wa = w1a[h * 8 + sub], wb = w1b[h * 8 + sub];
            A[h] = mxLo.x * wa.x + mxLo.y * wa.y + mxLo.z * wa.z + mxLo.w * wa.w
                 + mxHi.x * wb.x + mxHi.y * wb.y + mxHi.z * wb.z + mxHi.w * wb.w;
            float4 wa2 = w1a[(h + 8) * 8 + sub], wb2 = w1b[(h + 8) * 8 + sub];
            B[h] = mxLo.x * wa2.x + mxLo.y * wa2.y + mxLo.z * wa2.z + mxLo.w * wa2.w
                 + mxHi.x * wb2.x + mxHi.y * wb2.y + mxHi.z * wb2.z + mxHi.w * wb2.w;
        }
        fold8_2(A, B, sub);
        Hx_a = A[0]; Hx_b = B[0];
    }
    float H_a = fmaxf(Hm_a + b1a, 0.0f) + fmaxf(Hx_a + b1a, 0.0f);
    float H_b = fmaxf(Hm_b + b1b, 0.0f) + fmaxf(Hx_b + b1b, 0.0f);

    // layer 2: own 8 channels = sum_h H[h] * W2[h][c]
    float4 a0 = {0.f, 0.f, 0.f, 0.f}, a1 = {0.f, 0.f, 0.f, 0.f};
    #pragma unroll
    for (int h = 0; h < 8; ++h) {
        float Hh = __shfl(H_a, h, 8);
        float4 w0 = w2q[h * 16 + 2 * sub], w1v = w2q[h * 16 + 2 * sub + 1];
        a0.x += Hh * w0.x; a0.y += Hh * w0.y; a0.z += Hh * w0.z; a0.w += Hh * w0.w;
        a1.x += Hh * w1v.x; a1.y += Hh * w1v.y; a1.z += Hh * w1v.z; a1.w += Hh * w1v.w;
    }
    #pragma unroll
    for (int h = 0; h < 8; ++h) {
        float Hh = __shfl(H_b, h, 8);
        float4 w0 = w2q[(h + 8) * 16 + 2 * sub], w1v = w2q[(h + 8) * 16 + 2 * sub + 1];
        a0.x += Hh * w0.x; a0.y += Hh * w0.y; a0.z += Hh * w0.z; a0.w += Hh * w0.w;
        a1.x += Hh * w1v.x; a1.y += Hh * w1v.y; a1.z += Hh * w1v.z; a1.w += Hh * w1v.w;
    }
    float4 o0, o1;
    o0.x = own0.x * sigmoidf_(a0.x + 2.0f * bq0.x);
    o0.y = own0.y * sigmoidf_(a0.y + 2.0f * bq0.y);
    o0.z = own0.z * sigmoidf_(a0.z + 2.0f * bq0.z);
    o0.w = own0.w * sigmoidf_(a0.w + 2.0f * bq0.w);
    o1.x = own1.x * sigmoidf_(a1.x + 2.0f * bq1.x);
    o1.y = own1.y * sigmoidf_(a1.y + 2.0f * bq1.y);
    o1.z = own1.z * sigmoidf_(a1.z + 2.0f * bq1.z);
    o1.w = own1.w * sigmoidf_(a1.w + 2.0f * bq1.w);
    ntstore4(&outse[(size_t)p * 16 + 2 * sub], o0);
    ntstore4(&outse[(size_t)p * 16 + 2 * sub + 1], o1);

    // per-row stats for phase B (8B/neighbor there instead of 128B)
    float sm = (o0.x + o0.y + o0.z + o0.w) + (o1.x + o1.y + o1.z + o1.w);
    float sx = fmaxf(fmaxf(fmaxf(o0.x, o0.y), fmaxf(o0.z, o0.w)),
                     fmaxf(fmaxf(o1.x, o1.y), fmaxf(o1.z, o1.w)));
    #pragma unroll
    for (int m = 4; m >= 1; m >>= 1) {
        sm += __shfl_xor(sm, m);
        sx = fmaxf(sx, __shfl_xor(sx, m));
    }
    if (sub == 0) rowstat[p] = make_float2(sm * (1.0f / 64.0f), sx);
}

// Phase B: z[n] = (mean_k rowmean, max_k rowmax). 2 lanes per point.
// idx stream is zero-reuse -> nt; rowstat table (0.8 MB, L2-resident) stays
// cacheable.
__global__ __launch_bounds__(256) void kB(const int4* __restrict__ idxv,
        const float2* __restrict__ rowstat, float2* __restrict__ z, int n) {
    int t = blockIdx.x * 256 + threadIdx.x;
    int i = t >> 1, half = t & 1;
    if (i >= n) return;
    int4 a = ntload_i4(&idxv[(size_t)i * 4 + half * 2]);
    int4 b = ntload_i4(&idxv[(size_t)i * 4 + half * 2 + 1]);
    float2 s0 = rowstat[a.x], s1 = rowstat[a.y], s2 = rowstat[a.z], s3 = rowstat[a.w];
    float2 s4 = rowstat[b.x], s5 = rowstat[b.y], s6 = rowstat[b.z], s7 = rowstat[b.w];
    float zm = (s0.x + s1.x) + (s2.x + s3.x) + ((s4.x + s5.x) + (s6.x + s7.x));
    float zx = fmaxf(fmaxf(fmaxf(s0.y, s1.y), fmaxf(s2.y, s3.y)),
                     fmaxf(fmaxf(s4.y, s5.y), fmaxf(s6.y, s7.y)));
    zm += __shfl_xor(zm, 1);
    zx = fmaxf(zx, __shfl_xor(zx, 1));
    if (half == 0) z[i] = make_float2(zm * (1.0f / 16.0f), zx);
}

// Phase C (fused conv + scale): sig per point via LDS, then out = outse * sig.
// conv_idx is now staged through LDS with fully-coalesced nt loads (each
// thread's 27 ints were a stride-108B pattern before). outse/out streams nt;
// z table (0.8 MB, L2-resident) cacheable.
__global__ __launch_bounds__(256) void kC(const int* __restrict__ conv_idx,
        const float* __restrict__ conv_w, const float2* __restrict__ z,
        const float4* __restrict__ outse, float4* __restrict__ out, int n) {
    __shared__ float cw[54];
    __shared__ float sgate[256];
    __shared__ int sidx[256 * 27];
    if (threadIdx.x < 54) cw[threadIdx.x] = conv_w[threadIdx.x];
    int base = blockIdx.x * 256;
    int npts = n - base; if (npts > 256) npts = 256;
    for (int w = threadIdx.x; w < npts * 27; w += 256)
        sidx[w] = __builtin_nontemporal_load(&conv_idx[(size_t)base * 27 + w]);
    __syncthreads();
    int i = base + threadIdx.x;
    if (i < n) {
        float acc = 0.0f;
        #pragma unroll
        for (int k = 0; k < 27; ++k) {
            int j = sidx[threadIdx.x * 27 + k];     // branchless clamp + mask
            int jc = j >= 0 ? j : 0;
            float msk = j >= 0 ? 1.0f : 0.0f;
            float2 zz = z[jc];
            acc += msk * (zz.x * cw[2 * k] + zz.y * cw[2 * k + 1]);
        }
        sgate[threadIdx.x] = sigmoidf_(acc);
    }
    __syncthreads();
    int tot = npts * 16;                            // float4s this block owns
    for (int q = threadIdx.x; q < tot; q += 256) {
        float s = sgate[q >> 4];
        float4 v = ntload4(&outse[(size_t)base * 16 + q]);
        ntstore4(&out[(size_t)base * 16 + q],
                 make_float4(v.x * s, v.y * s, v.z * s, v.w * s));
    }
}

extern "C" void kernel_launch(void* const* d_in, const int* in_sizes, int n_in,
                              void* d_out, int out_size, void* d_ws, size_t ws_size,
                              hipStream_t stream) {
    const float* x_F    = (const float*)d_in[0];
    const float* W1     = (const float*)d_in[1];
    const float* b1     = (const float*)d_in[2];
    const float* W2     = (const float*)d_in[3];
    const float* b2     = (const float*)d_in[4];
    const float* conv_w = (const float*)d_in[5];
    const int*   idx    = (const int*)d_in[6];
    const int*   cidx   = (const int*)d_in[7];
    int n = in_sizes[0] / CH;   // 100000

    char* ws = (char*)d_ws;
    size_t off = 0;
    uint2*  xb      = (uint2*)(ws + off);  off += (size_t)n * CH * 2;   // bf16 table
    float*  outse   = (float*)(ws + off);  off += (size_t)n * CH * 4;
    float2* rowstat = (float2*)(ws + off); off += (size_t)n * 8;
    float2* zz      = (float2*)(ws + off); off += (size_t)n * 8;

    int n16 = n * 16;
    kX<<<(n16 + 255) / 256, 256, 0, stream>>>((const float4*)x_F, xb, n16);
    int blkA = (n + 31) / 32;
    kA<<<blkA, 256, 0, stream>>>((const float4*)x_F, (const uint4*)xb,
                                 W1, b1, W2, b2, (const int2*)idx,
                                 (float4*)outse, rowstat, n);
    int blkB = (2 * n + 255) / 256;
    kB<<<blkB, 256, 0, stream>>>((const int4*)idx, rowstat, zz, n);
    int blkP = (n + 255) / 256;
    kC<<<blkP, 256, 0, stream>>>(cidx, conv_w, zz, (const float4*)outse,
                                 (float4*)d_out, n);
}

// Round 3
// 176.735 us; speedup vs baseline: 1.1596x; 1.1596x over previous
//
#include <hip/hip_runtime.h>
#include <hip/hip_fp16.h>
#include <math.h>

#define KNN 16
#define CH 64
#define HID 16

__device__ __forceinline__ float sigmoidf_(float x) {
    return 1.0f / (1.0f + __expf(-x));
}

// pack two fp32 into bf16x2 (RNE), a in low16, b in high16
__device__ __forceinline__ unsigned int pack_bf2(float a, float b) {
    unsigned int ua = __float_as_uint(a), ub = __float_as_uint(b);
    ua = (ua + 0x7FFFu + ((ua >> 16) & 1u)) >> 16;
    ub = (ub + 0x7FFFu + ((ub >> 16) & 1u)) & 0xFFFF0000u;
    return ua | ub;
}

// unpack 4 packed bf16 -> float4
__device__ __forceinline__ float4 bf4_to_f4(unsigned int lo, unsigned int hi) {
    float4 r;
    r.x = __uint_as_float(lo << 16);
    r.y = __uint_as_float(lo & 0xFFFF0000u);
    r.z = __uint_as_float(hi << 16);
    r.w = __uint_as_float(hi & 0xFFFF0000u);
    return r;
}

// f16 pack/unpack for the gate (gate in (0,1): f16 rel err < 2^-11)
__device__ __forceinline__ unsigned int pack_h2(float a, float b) {
    __half2 h = __floats2half2_rn(a, b);
    return *(unsigned int*)&h;
}
__device__ __forceinline__ float2 unpack_h2(unsigned int u) {
    __half2 h;
    *(unsigned int*)&h = u;
    return __half22float2(h);
}

// paired fold-reduce across an 8-lane group: A[8],B[8] partials -> lane sub
// ends holding full sums A -> H[sub], B -> H[sub+8].
__device__ __forceinline__ void fold8_2(float A[8], float B[8], int sub) {
    #pragma unroll
    for (int m = 4; m >= 1; m >>= 1) {
        bool hi = (sub & m) != 0;
        #pragma unroll
        for (int i = 0; i < m; ++i) {
            float sA = hi ? A[i] : A[i + m], kA_ = hi ? A[i + m] : A[i];
            A[i] = kA_ + __shfl_xor(sA, m);
            float sB = hi ? B[i] : B[i + m], kB_ = hi ? B[i + m] : B[i];
            B[i] = kB_ + __shfl_xor(sB, m);
        }
    }
}

// Pre-pass: bf16 copy of x_F (halves gather lines + cache footprint for kA1).
// R2 lesson: NO nt hints anywhere — they bypass L3 and regressed everything.
__global__ __launch_bounds__(256) void kX(const float4* __restrict__ xv,
                                          uint2* __restrict__ xb, int n16) {
    int i = blockIdx.x * 256 + threadIdx.x;
    if (i >= n16) return;
    float4 v = xv[i];
    uint2 r;
    r.x = pack_bf2(v.x, v.y);
    r.y = pack_bf2(v.z, v.w);
    xb[i] = r;
}

// Phase A1: gathers + MLP -> gate only. 8 lanes per point, lane owns 8
// channels (uint4 = 8 bf16, 16B); one bf16 row = 128B = one 8-lane slice.
// R3 theory: kA's 60 us carried 32 MB of non-gather fetch (own fp32 rows +
// idx) and 26 MB of stores through the same ~3.2 TB/s window as the
// floor-limited gathers (87 MB = per-XCD coverage floor, measured). This
// kernel's window contains ONLY gathers + idx + a 12.8 MB f16 gate store.
// The fp32 own-row work moves to the streaming kA2 (R1's mistake — reading
// own rows from the TABLE — added gather misses; reading x elsewhere does not).
__global__ __launch_bounds__(256, 3) void kA1(const uint4* __restrict__ xb4,
        const float* __restrict__ W1, const float* __restrict__ b1,
        const float* __restrict__ W2, const float* __restrict__ b2,
        const int2* __restrict__ idx2,
        uint4* __restrict__ gateh, int n) {
    __shared__ float4 w1a[128];   // w1a[h*8+s] = W1[(8s+0..3)][h]
    __shared__ float4 w1b[128];   // w1b[h*8+s] = W1[(8s+4..7)][h]
    __shared__ float4 w2q[256];   // float4 copy of W2 (16x64 row-major)
    int t = threadIdx.x;
    if (t < 128) {
        int h = t >> 3, s = t & 7;
        float4 a, b;
        a.x = W1[(8 * s + 0) * HID + h];
        a.y = W1[(8 * s + 1) * HID + h];
        a.z = W1[(8 * s + 2) * HID + h];
        a.w = W1[(8 * s + 3) * HID + h];
        b.x = W1[(8 * s + 4) * HID + h];
        b.y = W1[(8 * s + 5) * HID + h];
        b.z = W1[(8 * s + 6) * HID + h];
        b.w = W1[(8 * s + 7) * HID + h];
        w1a[t] = a;
        w1b[t] = b;
    }
    w2q[t] = ((const float4*)W2)[t];
    __syncthreads();

    int p = blockIdx.x * 32 + (t >> 3);
    int sub = t & 7;
    if (p >= n) return;

    // 16 neighbor indices live as int2 per lane; broadcast via width-8 shfl
    int2 jp = idx2[(size_t)p * 8 + sub];
    int jA[8], jB[8];
    #pragma unroll
    for (int s = 0; s < 8; ++s) {
        jA[s] = __shfl(jp.x, s, 8);
        jB[s] = __shfl(jp.y, s, 8);
    }

    // issue all 16 gathers + bias loads, then pin with sched_barrier
    // (serialized issue measured 0.7 TB/s vs ~2.0 TB/s batched)
    uint4 va[8], vb[8];
    #pragma unroll
    for (int s = 0; s < 8; ++s) va[s] = xb4[(size_t)jA[s] * 8 + sub];
    #pragma unroll
    for (int s = 0; s < 8; ++s) vb[s] = xb4[(size_t)jB[s] * 8 + sub];
    float b1a = b1[sub], b1b = b1[sub + 8];
    float4 bq0 = ((const float4*)b2)[2 * sub];
    float4 bq1 = ((const float4*)b2)[2 * sub + 1];
    __builtin_amdgcn_sched_barrier(0);

    float4 sumLo, sumHi, mxLo, mxHi;
    {
        float4 lo = bf4_to_f4(va[0].x, va[0].y);
        float4 hi = bf4_to_f4(va[0].z, va[0].w);
        sumLo = lo; mxLo = lo; sumHi = hi; mxHi = hi;
    }
    #pragma unroll
    for (int s = 1; s < 8; ++s) {
        float4 lo = bf4_to_f4(va[s].x, va[s].y);
        float4 hi = bf4_to_f4(va[s].z, va[s].w);
        sumLo.x += lo.x; sumLo.y += lo.y; sumLo.z += lo.z; sumLo.w += lo.w;
        sumHi.x += hi.x; sumHi.y += hi.y; sumHi.z += hi.z; sumHi.w += hi.w;
        mxLo.x = fmaxf(mxLo.x, lo.x); mxLo.y = fmaxf(mxLo.y, lo.y);
        mxLo.z = fmaxf(mxLo.z, lo.z); mxLo.w = fmaxf(mxLo.w, lo.w);
        mxHi.x = fmaxf(mxHi.x, hi.x); mxHi.y = fmaxf(mxHi.y, hi.y);
        mxHi.z = fmaxf(mxHi.z, hi.z); mxHi.w = fmaxf(mxHi.w, hi.w);
    }
    #pragma unroll
    for (int s = 0; s < 8; ++s) {
        float4 lo = bf4_to_f4(vb[s].x, vb[s].y);
        float4 hi = bf4_to_f4(vb[s].z, vb[s].w);
        sumLo.x += lo.x; sumLo.y += lo.y; sumLo.z += lo.z; sumLo.w += lo.w;
        sumHi.x += hi.x; sumHi.y += hi.y; sumHi.z += hi.z; sumHi.w += hi.w;
        mxLo.x = fmaxf(mxLo.x, lo.x); mxLo.y = fmaxf(mxLo.y, lo.y);
        mxLo.z = fmaxf(mxLo.z, lo.z); mxLo.w = fmaxf(mxLo.w, lo.w);
        mxHi.x = fmaxf(mxHi.x, hi.x); mxHi.y = fmaxf(mxHi.y, hi.y);
        mxHi.z = fmaxf(mxHi.z, hi.z); mxHi.w = fmaxf(mxHi.w, hi.w);
    }
    const float inv_k = 1.0f / KNN;
    float4 meLo = {sumLo.x * inv_k, sumLo.y * inv_k, sumLo.z * inv_k, sumLo.w * inv_k};
    float4 meHi = {sumHi.x * inv_k, sumHi.y * inv_k, sumHi.z * inv_k, sumHi.w * inv_k};

    // layer 1: mean path then max path; fold over the 8-lane group
    float Hm_a, Hm_b, Hx_a, Hx_b;
    {
        float A[8], B[8];
        #pragma unroll
        for (int h = 0; h < 8; ++h) {
            float4 wa = w1a[h * 8 + sub], wb = w1b[h * 8 + sub];
            A[h] = meLo.x * wa.x + meLo.y * wa.y + meLo.z * wa.z + meLo.w * wa.w
                 + meHi.x * wb.x + meHi.y * wb.y + meHi.z * wb.z + meHi.w * wb.w;
            float4 wa2 = w1a[(h + 8) * 8 + sub], wb2 = w1b[(h + 8) * 8 + sub];
            B[h] = meLo.x * wa2.x + meLo.y * wa2.y + meLo.z * wa2.z + meLo.w * wa2.w
                 + meHi.x * wb2.x + meHi.y * wb2.y + meHi.z * wb2.z + meHi.w * wb2.w;
        }
        fold8_2(A, B, sub);
        Hm_a = A[0]; Hm_b = B[0];
    }
    {
        float A[8], B[8];
        #pragma unroll
        for (int h = 0; h < 8; ++h) {
            float4 wa = w1a[h * 8 + sub], wb = w1b[h * 8 + sub];
            A[h] = mxLo.x * wa.x + mxLo.y * wa.y + mxLo.z * wa.z + mxLo.w * wa.w
                 + mxHi.x * wb.x + mxHi.y * wb.y + mxHi.z * wb.z + mxHi.w * wb.w;
            float4 wa2 = w1a[(h + 8) * 8 + sub], wb2 = w1b[(h + 8) * 8 + sub];
            B[h] = mxLo.x * wa2.x + mxLo.y * wa2.y + mxLo.z * wa2.z + mxLo.w * wa2.w
                 + mxHi.x * wb2.x + mxHi.y * wb2.y + mxHi.z * wb2.z + mxHi.w * wb2.w;
        }
        fold8_2(A, B, sub);
        Hx_a = A[0]; Hx_b = B[0];
    }
    float H_a = fmaxf(Hm_a + b1a, 0.0f) + fmaxf(Hx_a + b1a, 0.0f);
    float H_b = fmaxf(Hm_b + b1b, 0.0f) + fmaxf(Hx_b + b1b, 0.0f);

    // layer 2: own 8 channels = sum_h H[h] * W2[h][c]
    float4 a0 = {0.f, 0.f, 0.f, 0.f}, a1 = {0.f, 0.f, 0.f, 0.f};
    #pragma unroll
    for (int h = 0; h < 8; ++h) {
        float Hh = __shfl(H_a, h, 8);
        float4 w0 = w2q[h * 16 + 2 * sub], w1v = w2q[h * 16 + 2 * sub + 1];
        a0.x += Hh * w0.x; a0.y += Hh * w0.y; a0.z += Hh * w0.z; a0.w += Hh * w0.w;
        a1.x += Hh * w1v.x; a1.y += Hh * w1v.y; a1.z += Hh * w1v.z; a1.w += Hh * w1v.w;
    }
    #pragma unroll
    for (int h = 0; h < 8; ++h) {
        float Hh = __shfl(H_b, h, 8);
        float4 w0 = w2q[(h + 8) * 16 + 2 * sub], w1v = w2q[(h + 8) * 16 + 2 * sub + 1];
        a0.x += Hh * w0.x; a0.y += Hh * w0.y; a0.z += Hh * w0.z; a0.w += Hh * w0.w;
        a1.x += Hh * w1v.x; a1.y += Hh * w1v.y; a1.z += Hh * w1v.z; a1.w += Hh * w1v.w;
    }

    // gate for this lane's 8 channels, stored f16 (channels 8*sub+0..7)
    float s0 = sigmoidf_(a0.x + 2.0f * bq0.x);
    float s1 = sigmoidf_(a0.y + 2.0f * bq0.y);
    float s2 = sigmoidf_(a0.z + 2.0f * bq0.z);
    float s3 = sigmoidf_(a0.w + 2.0f * bq0.w);
    float s4 = sigmoidf_(a1.x + 2.0f * bq1.x);
    float s5 = sigmoidf_(a1.y + 2.0f * bq1.y);
    float s6 = sigmoidf_(a1.z + 2.0f * bq1.z);
    float s7 = sigmoidf_(a1.w + 2.0f * bq1.w);
    uint4 gv;
    gv.x = pack_h2(s0, s1);
    gv.y = pack_h2(s2, s3);
    gv.z = pack_h2(s4, s5);
    gv.w = pack_h2(s6, s7);
    gateh[(size_t)p * 8 + sub] = gv;
}

// Phase A2 (streaming): rowstat from fp32 x * f16 gate. 8 lanes/point,
// fully coalesced (wave = 8 points = contiguous 2KB of x + 1KB of gate).
__global__ __launch_bounds__(256) void kA2(const float4* __restrict__ xv,
        const uint4* __restrict__ gateh, float2* __restrict__ rowstat, int n) {
    int t = threadIdx.x;
    int p = blockIdx.x * 32 + (t >> 3);
    int sub = t & 7;
    if (p >= n) return;
    float4 own0 = xv[(size_t)p * 16 + 2 * sub];
    float4 own1 = xv[(size_t)p * 16 + 2 * sub + 1];
    uint4 g = gateh[(size_t)p * 8 + sub];
    float2 g0 = unpack_h2(g.x), g1 = unpack_h2(g.y);
    float2 g2 = unpack_h2(g.z), g3 = unpack_h2(g.w);
    float o0 = own0.x * g0.x, o1 = own0.y * g0.y;
    float o2 = own0.z * g1.x, o3 = own0.w * g1.y;
    float o4 = own1.x * g2.x, o5 = own1.y * g2.y;
    float o6 = own1.z * g3.x, o7 = own1.w * g3.y;
    float sm = (o0 + o1) + (o2 + o3) + ((o4 + o5) + (o6 + o7));
    float sx = fmaxf(fmaxf(fmaxf(o0, o1), fmaxf(o2, o3)),
                     fmaxf(fmaxf(o4, o5), fmaxf(o6, o7)));
    #pragma unroll
    for (int m = 4; m >= 1; m >>= 1) {
        sm += __shfl_xor(sm, m);
        sx = fmaxf(sx, __shfl_xor(sx, m));
    }
    if (sub == 0) rowstat[p] = make_float2(sm * (1.0f / 64.0f), sx);
}

// Phase B: z[n] = (mean_k rowmean, max_k rowmax). 2 lanes per point.
__global__ __launch_bounds__(256) void kB(const int4* __restrict__ idxv,
        const float2* __restrict__ rowstat, float2* __restrict__ z, int n) {
    int t = blockIdx.x * 256 + threadIdx.x;
    int i = t >> 1, half = t & 1;
    if (i >= n) return;
    int4 a = idxv[(size_t)i * 4 + half * 2];
    int4 b = idxv[(size_t)i * 4 + half * 2 + 1];
    float2 s0 = rowstat[a.x], s1 = rowstat[a.y], s2 = rowstat[a.z], s3 = rowstat[a.w];
    float2 s4 = rowstat[b.x], s5 = rowstat[b.y], s6 = rowstat[b.z], s7 = rowstat[b.w];
    float zm = (s0.x + s1.x) + (s2.x + s3.x) + ((s4.x + s5.x) + (s6.x + s7.x));
    float zx = fmaxf(fmaxf(fmaxf(s0.y, s1.y), fmaxf(s2.y, s3.y)),
                     fmaxf(fmaxf(s4.y, s5.y), fmaxf(s6.y, s7.y)));
    zm += __shfl_xor(zm, 1);
    zx = fmaxf(zx, __shfl_xor(zx, 1));
    if (half == 0) z[i] = make_float2(zm * (1.0f / 16.0f), zx);
}

// Phase C (fused conv + scale): sig per point via LDS, then
// out = x_F(fp32) * gate(f16) * sig — outse is never materialized.
__global__ __launch_bounds__(256) void kC(const int* __restrict__ conv_idx,
        const float* __restrict__ conv_w, const float2* __restrict__ z,
        const float4* __restrict__ xv, const uint2* __restrict__ gh,
        float4* __restrict__ out, int n) {
    __shared__ float cw[54];
    __shared__ float sgate[256];
    if (threadIdx.x < 54) cw[threadIdx.x] = conv_w[threadIdx.x];
    __syncthreads();
    int base = blockIdx.x * 256;
    int i = base + threadIdx.x;
    if (i < n) {
        float acc = 0.0f;
        #pragma unroll
        for (int k = 0; k < 27; ++k) {
            int j = conv_idx[(size_t)i * 27 + k];   // branchless clamp + mask
            int jc = j >= 0 ? j : 0;
            float msk = j >= 0 ? 1.0f : 0.0f;
            float2 zz = z[jc];
            acc += msk * (zz.x * cw[2 * k] + zz.y * cw[2 * k + 1]);
        }
        sgate[threadIdx.x] = sigmoidf_(acc);
    }
    __syncthreads();
    int npts = n - base; if (npts > 256) npts = 256;
    int tot = npts * 16;                            // float4s this block owns
    for (int q = threadIdx.x; q < tot; q += 256) {
        float s = sgate[q >> 4];
        size_t Q = (size_t)base * 16 + q;
        float4 v = xv[Q];
        uint2 g = gh[Q];
        float2 gl = unpack_h2(g.x);
        float2 gu = unpack_h2(g.y);
        out[Q] = make_float4(v.x * gl.x * s, v.y * gl.y * s,
                             v.z * gu.x * s, v.w * gu.y * s);
    }
}

extern "C" void kernel_launch(void* const* d_in, const int* in_sizes, int n_in,
                              void* d_out, int out_size, void* d_ws, size_t ws_size,
                              hipStream_t stream) {
    const float* x_F    = (const float*)d_in[0];
    const float* W1     = (const float*)d_in[1];
    const float* b1     = (const float*)d_in[2];
    const float* W2     = (const float*)d_in[3];
    const float* b2     = (const float*)d_in[4];
    const float* conv_w = (const float*)d_in[5];
    const int*   idx    = (const int*)d_in[6];
    const int*   cidx   = (const int*)d_in[7];
    int n = in_sizes[0] / CH;   // 100000

    char* ws = (char*)d_ws;
    size_t off = 0;
    uint2*  xb      = (uint2*)(ws + off);  off += (size_t)n * CH * 2;   // bf16 table
    uint4*  gateh   = (uint4*)(ws + off);  off += (size_t)n * CH * 2;   // f16 gate
    float2* rowstat = (float2*)(ws + off); off += (size_t)n * 8;
    float2* zz      = (float2*)(ws + off); off += (size_t)n * 8;

    int n16 = n * 16;
    kX<<<(n16 + 255) / 256, 256, 0, stream>>>((const float4*)x_F, xb, n16);
    int blkA = (n + 31) / 32;
    kA1<<<blkA, 256, 0, stream>>>((const uint4*)xb, W1, b1, W2, b2,
                                  (const int2*)idx, gateh, n);
    kA2<<<blkA, 256, 0, stream>>>((const float4*)x_F, gateh, rowstat, n);
    int blkB = (2 * n + 255) / 256;
    kB<<<blkB, 256, 0, stream>>>((const int4*)idx, rowstat, zz, n);
    int blkP = (n + 255) / 256;
    kC<<<blkP, 256, 0, stream>>>(cidx, conv_w, zz, (const float4*)x_F,
                                 (const uint2*)gateh, (float4*)d_out, n);
}